// Round 1
// baseline (747.790 us; speedup 1.0000x reference)
//
#include <hip/hip_runtime.h>
#include <cstdint>
#include <cstddef>

#define SEQ 1024
#define DM 1024
#define DF 4096
#define NH 16
#define DH 64
#define BSZ 4
#define NTOK (BSZ*SEQ)

typedef short s16x8 __attribute__((ext_vector_type(8)));
typedef float f32x4 __attribute__((ext_vector_type(4)));

__device__ __forceinline__ unsigned short f2bf(float f) {
  union { float f; unsigned u; } c; c.f = f;
  unsigned u = c.u;
  return (unsigned short)((u + 0x7fffu + ((u >> 16) & 1u)) >> 16);
}

__device__ __forceinline__ void gll16(const void* g, void* l) {
  __builtin_amdgcn_global_load_lds(
      (__attribute__((address_space(1))) void*)(g),
      (__attribute__((address_space(3))) void*)(l), 16, 0, 0);
}

// ---------------------------------------------------------------------------
// Generic bf16 MFMA GEMM: C[m,n] = sum_k A[m,k] * W[n,k]  (+ epilogue)
// A: [M x K] bf16 row stride aRow; W: [N x K] bf16 row stride wRow.
// grid.x = mBlocks*nBlocks, grid.y/z add affine offsets (batched attention PV).
// EPI: 0 = bf16 store (val+bias)*scale
//      1 = bf16 store relu(val+bias)
//      2 = bf16 store TRANSPOSED per batch: out[b][n][s] (V^T for PV)
//      3 = f32 store val+bias+resid
//      4 = f32 store raw (unused currently)
// ---------------------------------------------------------------------------
template<int BM, int BN, int WM, int WN, int EPI>
__launch_bounds__(256)
__global__ void gemm_k(const unsigned short* __restrict__ A,
                       const unsigned short* __restrict__ W,
                       const float* __restrict__ bias,
                       void* __restrict__ outp,
                       const float* __restrict__ resid,
                       int nB, int K, int aRow, int wRow, int oRow,
                       long aY, long aZ, long wY, long wZ,
                       long oY, long oZ, long rY, long rZ, float scale) {
  constexpr int BK = 32;
  __shared__ unsigned short At[BM*BK];
  __shared__ unsigned short Wt[BN*BK];
  const int tid = threadIdx.x;
  const int mb = (int)blockIdx.x / nB, nb = (int)blockIdx.x % nB;
  const long aBase = (long)blockIdx.y*aY + (long)blockIdx.z*aZ + (long)mb*BM*aRow;
  const long wBase = (long)blockIdx.y*wY + (long)blockIdx.z*wZ + (long)nb*BN*wRow;
  const int wave = tid >> 6, lane = tid & 63;
  const int quad = lane >> 4, l16 = lane & 15;
  constexpr int WGN = BN / WN;
  const int wm = (wave / WGN) * WM, wn = (wave % WGN) * WN;
  constexpr int MT = WM/16, NT = WN/16;
  f32x4 acc[MT][NT] = {};
  const int srow = tid >> 2, skof = (tid & 3) * 8;

  for (int k0 = 0; k0 < K; k0 += BK) {
#pragma unroll
    for (int r = 0; r < BM; r += 64)
      gll16(A + aBase + (long)(r + srow)*aRow + k0 + skof, &At[(r + srow)*BK + skof]);
#pragma unroll
    for (int r = 0; r < BN; r += 64)
      gll16(W + wBase + (long)(r + srow)*wRow + k0 + skof, &Wt[(r + srow)*BK + skof]);
    __syncthreads();
    s16x8 af[MT];
#pragma unroll
    for (int mt = 0; mt < MT; ++mt)
      af[mt] = *(const s16x8*)&At[(wm + mt*16 + l16)*BK + quad*8];
#pragma unroll
    for (int nt = 0; nt < NT; ++nt) {
      s16x8 bfr = *(const s16x8*)&Wt[(wn + nt*16 + l16)*BK + quad*8];
#pragma unroll
      for (int mt = 0; mt < MT; ++mt)
        acc[mt][nt] = __builtin_amdgcn_mfma_f32_16x16x32_bf16(af[mt], bfr, acc[mt][nt], 0, 0, 0);
    }
    __syncthreads();
  }

  const long oBase = (long)blockIdx.y*oY + (long)blockIdx.z*oZ;
  const long rBase = (long)blockIdx.y*rY + (long)blockIdx.z*rZ;
#pragma unroll
  for (int mt = 0; mt < MT; ++mt) {
#pragma unroll
    for (int nt = 0; nt < NT; ++nt) {
      const int gn = nb*BN + wn + nt*16 + l16;
      const float bv = bias ? bias[gn] : 0.f;
#pragma unroll
      for (int r = 0; r < 4; ++r) {
        const int gm = mb*BM + wm + mt*16 + quad*4 + r;
        float v = acc[mt][nt][r] + bv;
        if (EPI == 0) {
          ((unsigned short*)outp)[oBase + (long)gm*oRow + gn] = f2bf(v * scale);
        } else if (EPI == 1) {
          ((unsigned short*)outp)[oBase + (long)gm*oRow + gn] = f2bf(v > 0.f ? v : 0.f);
        } else if (EPI == 2) {
          const int bb = gm >> 10, s = gm & 1023;
          ((unsigned short*)outp)[(long)bb*DM*SEQ + (long)gn*SEQ + s] = f2bf(v);
        } else if (EPI == 3) {
          const long o = oBase + (long)gm*oRow + gn;
          ((float*)outp)[o] = v + resid[rBase + (long)gm*oRow + gn];
        } else {
          ((float*)outp)[oBase + (long)gm*oRow + gn] = v;
        }
      }
    }
  }
}

// ---------------------------------------------------------------------------
// LayerNorm (torch-style: unbiased var ddof=1, divide by (std + eps)), f32 in,
// bf16 out. One block per token row of 1024.
// ---------------------------------------------------------------------------
__launch_bounds__(256)
__global__ void ln_k(const float* __restrict__ x, const float* __restrict__ g,
                     const float* __restrict__ bta, unsigned short* __restrict__ out) {
  const int row = blockIdx.x, t = threadIdx.x;
  const float4 v = ((const float4*)(x + (long)row*DM))[t];
  __shared__ float red[4];
  float s = v.x + v.y + v.z + v.w;
#pragma unroll
  for (int o = 32; o; o >>= 1) s += __shfl_down(s, o);
  if ((t & 63) == 0) red[t >> 6] = s;
  __syncthreads();
  const float mean = (red[0] + red[1] + red[2] + red[3]) * (1.f/1024.f);
  __syncthreads();
  const float dx = v.x - mean, dy = v.y - mean, dz = v.z - mean, dw = v.w - mean;
  float sq = dx*dx + dy*dy + dz*dz + dw*dw;
#pragma unroll
  for (int o = 32; o; o >>= 1) sq += __shfl_down(sq, o);
  if ((t & 63) == 0) red[t >> 6] = sq;
  __syncthreads();
  const float var = (red[0] + red[1] + red[2] + red[3]) * (1.f/1023.f);
  const float inv = 1.f / (sqrtf(var) + 1e-12f);
  const float4 gv = ((const float4*)g)[t];
  const float4 bv = ((const float4*)bta)[t];
  ushort4 o4;
  o4.x = f2bf(gv.x * dx * inv + bv.x);
  o4.y = f2bf(gv.y * dy * inv + bv.y);
  o4.z = f2bf(gv.z * dz * inv + bv.z);
  o4.w = f2bf(gv.w * dw * inv + bv.w);
  ((ushort4*)(out + (long)row*DM))[t] = o4;
}

// f32 -> bf16 elementwise
__launch_bounds__(256)
__global__ void cvt_k(const float* __restrict__ in, unsigned short* __restrict__ out, int n4) {
  const int i = blockIdx.x*256 + threadIdx.x;
  if (i < n4) {
    const float4 v = ((const float4*)in)[i];
    ushort4 o; o.x = f2bf(v.x); o.y = f2bf(v.y); o.z = f2bf(v.z); o.w = f2bf(v.w);
    ((ushort4*)out)[i] = o;
  }
}

// ---------------------------------------------------------------------------
// Fused scores + softmax. One block = 16 q rows x all 1024 k cols for one
// (b,h). Wave w owns cols [w*256, w*256+256). Q pre-scaled by 0.125.
// Writes normalized attn as f32 to d_out ([H,B,S,S]) and bf16 to ws.
// ---------------------------------------------------------------------------
__launch_bounds__(256)
__global__ void attn_k(const unsigned short* __restrict__ Q,
                       const unsigned short* __restrict__ Kb,
                       float* __restrict__ attn_f,
                       unsigned short* __restrict__ attn_b) {
  const int b = blockIdx.y, h = blockIdx.z;
  const int q0 = blockIdx.x * 16;
  const int wave = threadIdx.x >> 6, lane = threadIdx.x & 63;
  const int quad = lane >> 4, l16 = lane & 15;
  const unsigned short* Qb = Q + (long)b*SEQ*DM + h*DH;
  const unsigned short* Kh = Kb + (long)b*SEQ*DM + h*DH;
  s16x8 af[2];
#pragma unroll
  for (int ks = 0; ks < 2; ++ks)
    af[ks] = *(const s16x8*)&Qb[(long)(q0 + l16)*DM + ks*32 + quad*8];
  f32x4 acc[16];
#pragma unroll
  for (int nt = 0; nt < 16; ++nt) acc[nt] = (f32x4){0.f, 0.f, 0.f, 0.f};
  for (int nt = 0; nt < 16; ++nt) {
    const int kc = wave*256 + nt*16 + l16;
#pragma unroll
    for (int ks = 0; ks < 2; ++ks) {
      const s16x8 bfr = *(const s16x8*)&Kh[(long)kc*DM + ks*32 + quad*8];
      acc[nt] = __builtin_amdgcn_mfma_f32_16x16x32_bf16(af[ks], bfr, acc[nt], 0, 0, 0);
    }
  }
  __shared__ float red[4][16];
  float rmax[4];
#pragma unroll
  for (int r = 0; r < 4; ++r) {
    float m = -3e38f;
#pragma unroll
    for (int nt = 0; nt < 16; ++nt) m = fmaxf(m, acc[nt][r]);
#pragma unroll
    for (int o = 1; o < 16; o <<= 1) m = fmaxf(m, __shfl_xor(m, o));
    rmax[r] = m;
  }
  if (l16 == 0) {
#pragma unroll
    for (int r = 0; r < 4; ++r) red[wave][quad*4 + r] = rmax[r];
  }
  __syncthreads();
#pragma unroll
  for (int r = 0; r < 4; ++r)
    rmax[r] = fmaxf(fmaxf(red[0][quad*4+r], red[1][quad*4+r]),
                    fmaxf(red[2][quad*4+r], red[3][quad*4+r]));
  __syncthreads();
#pragma unroll
  for (int r = 0; r < 4; ++r) {
    float s = 0.f;
#pragma unroll
    for (int nt = 0; nt < 16; ++nt) {
      const float e = __expf(acc[nt][r] - rmax[r]);
      acc[nt][r] = e; s += e;
    }
#pragma unroll
    for (int o = 1; o < 16; o <<= 1) s += __shfl_xor(s, o);
    if (l16 == 0) red[wave][quad*4 + r] = s;
  }
  __syncthreads();
  const long obase = (long)(h*BSZ + b)*SEQ*SEQ;
#pragma unroll
  for (int r = 0; r < 4; ++r) {
    const float tot = red[0][quad*4+r] + red[1][quad*4+r] + red[2][quad*4+r] + red[3][quad*4+r];
    const float inv = 1.f / tot;
    const long rowoff = obase + (long)(q0 + quad*4 + r)*SEQ;
#pragma unroll
    for (int nt = 0; nt < 16; ++nt) {
      const int col = wave*256 + nt*16 + l16;
      const float v = acc[nt][r] * inv;
      attn_f[rowoff + col] = v;
      attn_b[rowoff + col] = f2bf(v);
    }
  }
}

extern "C" void kernel_launch(void* const* d_in, const int* in_sizes, int n_in,
                              void* d_out, int out_size, void* d_ws, size_t ws_size,
                              hipStream_t stream) {
  const float* x    = (const float*)d_in[0];
  const float* ln1g = (const float*)d_in[1];
  const float* ln1b = (const float*)d_in[2];
  const float* wq   = (const float*)d_in[3];
  const float* bq   = (const float*)d_in[4];
  const float* wk   = (const float*)d_in[5];
  const float* bk   = (const float*)d_in[6];
  const float* wv   = (const float*)d_in[7];
  const float* bv   = (const float*)d_in[8];
  const float* ln2g = (const float*)d_in[9];
  const float* ln2b = (const float*)d_in[10];
  const float* w1   = (const float*)d_in[11];
  const float* b1   = (const float*)d_in[12];
  const float* w2   = (const float*)d_in[13];
  const float* b2   = (const float*)d_in[14];
  float* out    = (float*)d_out;
  float* attn_f = out + (long)NTOK*DM;

  uint8_t* p = (uint8_t*)d_ws;
  auto alloc = [&](size_t bytes) {
    uint8_t* r = p; p += (bytes + 255) & ~(size_t)255; return r;
  };
  unsigned short* hbuf  = (unsigned short*)alloc((size_t)NTOK*DM*2);   // LN1(x)
  unsigned short* qbuf  = (unsigned short*)alloc((size_t)NTOK*DM*2);   // Q*0.125
  unsigned short* kbuf  = (unsigned short*)alloc((size_t)NTOK*DM*2);   // K
  unsigned short* vt    = (unsigned short*)alloc((size_t)BSZ*DM*SEQ*2);// V^T per batch
  unsigned short* h2    = (unsigned short*)alloc((size_t)NTOK*DM*2);   // LN2(out1)
  unsigned short* f1    = (unsigned short*)alloc((size_t)NTOK*DF*2);   // relu(ff1)
  float*          out1  = (float*)alloc((size_t)NTOK*DM*4);            // ctx + x
  unsigned short* attnb = (unsigned short*)alloc((size_t)NH*BSZ*SEQ*SEQ*2);
  unsigned short* wqb   = (unsigned short*)alloc((size_t)DM*DM*2);
  unsigned short* wkb   = (unsigned short*)alloc((size_t)DM*DM*2);
  unsigned short* wvb   = (unsigned short*)alloc((size_t)DM*DM*2);
  unsigned short* w1b   = (unsigned short*)alloc((size_t)DF*DM*2);
  unsigned short* w2b   = (unsigned short*)alloc((size_t)DM*DF*2);

  // 1. weights -> bf16
  cvt_k<<<DM*DM/4/256, 256, 0, stream>>>(wq, wqb, DM*DM/4);
  cvt_k<<<DM*DM/4/256, 256, 0, stream>>>(wk, wkb, DM*DM/4);
  cvt_k<<<DM*DM/4/256, 256, 0, stream>>>(wv, wvb, DM*DM/4);
  cvt_k<<<DF*DM/4/256, 256, 0, stream>>>(w1, w1b, DF*DM/4);
  cvt_k<<<DM*DF/4/256, 256, 0, stream>>>(w2, w2b, DM*DF/4);

  // 2. LN1
  ln_k<<<NTOK, 256, 0, stream>>>(x, ln1g, ln1b, hbuf);

  // 3. Q, K, V projections (Q pre-scaled by 1/sqrt(DH); V stored transposed)
  gemm_k<128,128,64,64,0><<<dim3((NTOK/128)*(DM/128)), 256, 0, stream>>>(
      hbuf, wqb, bq, qbuf, nullptr, DM/128, DM, DM, DM, DM,
      0,0,0,0,0,0,0,0, 0.125f);
  gemm_k<128,128,64,64,0><<<dim3((NTOK/128)*(DM/128)), 256, 0, stream>>>(
      hbuf, wkb, bk, kbuf, nullptr, DM/128, DM, DM, DM, DM,
      0,0,0,0,0,0,0,0, 1.f);
  gemm_k<128,128,64,64,2><<<dim3((NTOK/128)*(DM/128)), 256, 0, stream>>>(
      hbuf, wvb, bv, vt, nullptr, DM/128, DM, DM, DM, DM,
      0,0,0,0,0,0,0,0, 1.f);

  // 4. scores + softmax -> attn (f32 out, bf16 scratch)
  attn_k<<<dim3(SEQ/16, BSZ, NH), 256, 0, stream>>>(qbuf, kbuf, attn_f, attnb);

  // 5. ctx = attn @ V, + residual x -> out1 (f32)
  gemm_k<128,64,32,64,3><<<dim3(SEQ/128, BSZ, NH), 256, 0, stream>>>(
      attnb, vt, nullptr, out1, x, 1, SEQ, SEQ, SEQ, DM,
      (long)SEQ*SEQ, (long)BSZ*SEQ*SEQ,
      (long)DM*SEQ, (long)DH*SEQ,
      (long)SEQ*DM, (long)DH,
      (long)SEQ*DM, (long)DH, 1.f);

  // 6. LN2
  ln_k<<<NTOK, 256, 0, stream>>>(out1, ln2g, ln2b, h2);

  // 7. ff1 = relu(h2 @ w1^T + b1)
  gemm_k<128,128,64,64,1><<<dim3((NTOK/128)*(DF/128)), 256, 0, stream>>>(
      h2, w1b, b1, f1, nullptr, DF/128, DM, DM, DM, DF,
      0,0,0,0,0,0,0,0, 1.f);

  // 8. out = ff1 @ w2^T + b2 + out1 -> d_out
  gemm_k<128,128,64,64,3><<<dim3((NTOK/128)*(DM/128)), 256, 0, stream>>>(
      f1, w2b, b2, out, out1, DM/128, DF, DF, DF, DM,
      0,0,0,0,0,0,0,0, 1.f);
}

// Round 2
// 687.174 us; speedup vs baseline: 1.0882x; 1.0882x over previous
//
#include <hip/hip_runtime.h>
#include <cstdint>
#include <cstddef>

#define SEQ 1024
#define DM 1024
#define DF 4096
#define NH 16
#define DH 64
#define BSZ 4
#define NTOK (BSZ*SEQ)
#define QKVSZ ((long)NTOK*DM)   // elems per Q/K/V plane

typedef short s16x8 __attribute__((ext_vector_type(8)));
typedef float f32x4 __attribute__((ext_vector_type(4)));

__device__ __forceinline__ unsigned short f2bf(float f) {
  union { float f; unsigned u; } c; c.f = f;
  unsigned u = c.u;
  return (unsigned short)((u + 0x7fffu + ((u >> 16) & 1u)) >> 16);
}
__device__ __forceinline__ float bf2f(unsigned short b) {
  union { unsigned u; float f; } c; c.u = ((unsigned)b) << 16; return c.f;
}

__device__ __forceinline__ void gll16(const void* g, void* l) {
  __builtin_amdgcn_global_load_lds(
      (__attribute__((address_space(1))) void*)(g),
      (__attribute__((address_space(3))) void*)(l), 16, 0, 0);
}

// ---------------------------------------------------------------------------
// Generic bf16 MFMA GEMM: C[m,n] = sum_k A[m,k] * W[n,k]  (+ epilogue)
// EPI: 1 = bf16 store relu(val+bias)
//      3 = f32 store val+bias+resid
//      5 = fused QKV: gn in [0,1024) -> Q*scale bf16; [1024,2048) -> K bf16;
//          [2048,3072) -> V transposed per batch (vt[b][col][s])
// ---------------------------------------------------------------------------
template<int BM, int BN, int WM, int WN, int EPI>
__launch_bounds__(256)
__global__ void gemm_k(const unsigned short* __restrict__ A,
                       const unsigned short* __restrict__ W,
                       const float* __restrict__ bias,
                       void* __restrict__ outp,
                       const float* __restrict__ resid,
                       int nB, int K, int aRow, int wRow, int oRow,
                       float scale) {
  constexpr int BK = 32;
  __shared__ unsigned short At[BM*BK];
  __shared__ unsigned short Wt[BN*BK];
  const int tid = threadIdx.x;
  const int mb = (int)blockIdx.x / nB, nb = (int)blockIdx.x % nB;
  const long aBase = (long)mb*BM*aRow;
  const long wBase = (long)nb*BN*wRow;
  const int wave = tid >> 6, lane = tid & 63;
  const int quad = lane >> 4, l16 = lane & 15;
  constexpr int WGN = BN / WN;
  const int wm = (wave / WGN) * WM, wn = (wave % WGN) * WN;
  constexpr int MT = WM/16, NT = WN/16;
  f32x4 acc[MT][NT] = {};
  const int srow = tid >> 2, skof = (tid & 3) * 8;

  for (int k0 = 0; k0 < K; k0 += BK) {
#pragma unroll
    for (int r = 0; r < BM; r += 64)
      gll16(A + aBase + (long)(r + srow)*aRow + k0 + skof, &At[(r + srow)*BK + skof]);
#pragma unroll
    for (int r = 0; r < BN; r += 64)
      gll16(W + wBase + (long)(r + srow)*wRow + k0 + skof, &Wt[(r + srow)*BK + skof]);
    __syncthreads();
    s16x8 af[MT];
#pragma unroll
    for (int mt = 0; mt < MT; ++mt)
      af[mt] = *(const s16x8*)&At[(wm + mt*16 + l16)*BK + quad*8];
#pragma unroll
    for (int nt = 0; nt < NT; ++nt) {
      s16x8 bfr = *(const s16x8*)&Wt[(wn + nt*16 + l16)*BK + quad*8];
#pragma unroll
      for (int mt = 0; mt < MT; ++mt)
        acc[mt][nt] = __builtin_amdgcn_mfma_f32_16x16x32_bf16(af[mt], bfr, acc[mt][nt], 0, 0, 0);
    }
    __syncthreads();
  }

#pragma unroll
  for (int mt = 0; mt < MT; ++mt) {
#pragma unroll
    for (int nt = 0; nt < NT; ++nt) {
      const int gn = nb*BN + wn + nt*16 + l16;
      const float bv = bias ? bias[gn] : 0.f;
#pragma unroll
      for (int r = 0; r < 4; ++r) {
        const int gm = mb*BM + wm + mt*16 + quad*4 + r;
        float v = acc[mt][nt][r] + bv;
        if (EPI == 1) {
          ((unsigned short*)outp)[(long)gm*oRow + gn] = f2bf(v > 0.f ? v : 0.f);
        } else if (EPI == 3) {
          const long o = (long)gm*oRow + gn;
          ((float*)outp)[o] = v + resid[o];
        } else if (EPI == 5) {
          unsigned short* base = (unsigned short*)outp;
          const int reg = gn >> 10, cn = gn & 1023;
          if (reg == 0) {
            base[(long)gm*DM + cn] = f2bf(v * scale);
          } else if (reg == 1) {
            base[QKVSZ + (long)gm*DM + cn] = f2bf(v);
          } else {
            const int bb = gm >> 10, s = gm & 1023;
            base[2*QKVSZ + (long)bb*DM*SEQ + (long)cn*SEQ + s] = f2bf(v);
          }
        }
      }
    }
  }
}

// ---------------------------------------------------------------------------
// LayerNorm (torch-style: unbiased var ddof=1, divide by (std + eps)), f32 in,
// bf16 out. One block per token row of 1024.
// ---------------------------------------------------------------------------
__launch_bounds__(256)
__global__ void ln_k(const float* __restrict__ x, const float* __restrict__ g,
                     const float* __restrict__ bta, unsigned short* __restrict__ out) {
  const int row = blockIdx.x, t = threadIdx.x;
  const float4 v = ((const float4*)(x + (long)row*DM))[t];
  __shared__ float red[4];
  float s = v.x + v.y + v.z + v.w;
#pragma unroll
  for (int o = 32; o; o >>= 1) s += __shfl_down(s, o);
  if ((t & 63) == 0) red[t >> 6] = s;
  __syncthreads();
  const float mean = (red[0] + red[1] + red[2] + red[3]) * (1.f/1024.f);
  __syncthreads();
  const float dx = v.x - mean, dy = v.y - mean, dz = v.z - mean, dw = v.w - mean;
  float sq = dx*dx + dy*dy + dz*dz + dw*dw;
#pragma unroll
  for (int o = 32; o; o >>= 1) sq += __shfl_down(sq, o);
  if ((t & 63) == 0) red[t >> 6] = sq;
  __syncthreads();
  const float var = (red[0] + red[1] + red[2] + red[3]) * (1.f/1023.f);
  const float inv = 1.f / (sqrtf(var) + 1e-12f);
  const float4 gv = ((const float4*)g)[t];
  const float4 bv = ((const float4*)bta)[t];
  ushort4 o4;
  o4.x = f2bf(gv.x * dx * inv + bv.x);
  o4.y = f2bf(gv.y * dy * inv + bv.y);
  o4.z = f2bf(gv.z * dz * inv + bv.z);
  o4.w = f2bf(gv.w * dw * inv + bv.w);
  ((ushort4*)(out + (long)row*DM))[t] = o4;
}

// ---------------------------------------------------------------------------
// One-shot conversion of all weights (fp32 -> bf16, QKV concatenated) + bias
// concat. float4-indexed regions; last block copies biases.
// ---------------------------------------------------------------------------
#define R_WQ  262144L
#define R_WK  524288L
#define R_WV  786432L
#define R_W1  1835008L
#define R_W2  2883584L
#define CVT_BLOCKS 11265
__launch_bounds__(256)
__global__ void cvt5_k(const float* __restrict__ wq, const float* __restrict__ wk,
                       const float* __restrict__ wv, const float* __restrict__ w1,
                       const float* __restrict__ w2,
                       const float* __restrict__ bq, const float* __restrict__ bk,
                       const float* __restrict__ bvv,
                       unsigned short* __restrict__ wqkvb,
                       unsigned short* __restrict__ w1b,
                       unsigned short* __restrict__ w2b,
                       float* __restrict__ bcat) {
  const long blk = blockIdx.x;
  if (blk == CVT_BLOCKS - 1) {
    for (int j = threadIdx.x; j < 3072; j += 256)
      bcat[j] = j < 1024 ? bq[j] : (j < 2048 ? bk[j - 1024] : bvv[j - 2048]);
    return;
  }
  long i = blk*256 + threadIdx.x;
  const float* s; unsigned short* d;
  if (i < R_WQ)       { s = wq; d = wqkvb;              }
  else if (i < R_WK)  { s = wk; d = wqkvb + 1048576; i -= R_WQ; }
  else if (i < R_WV)  { s = wv; d = wqkvb + 2097152; i -= R_WK; }
  else if (i < R_W1)  { s = w1; d = w1b;             i -= R_WV; }
  else                { s = w2; d = w2b;             i -= R_W1; }
  const float4 v = ((const float4*)s)[i];
  ushort4 o; o.x = f2bf(v.x); o.y = f2bf(v.y); o.z = f2bf(v.z); o.w = f2bf(v.w);
  ((ushort4*)d)[i] = o;
}

// ---------------------------------------------------------------------------
// Fused scores + softmax + attn write + P@V + residual.
// Block = 16 q rows x one (b,h). Wave w owns score cols [w*256, w*256+256).
// After softmax, P (bf16) goes to LDS; attn output written coalesced from
// LDS; PV read A-frags from LDS, B-frags (V^T) from global (L2-resident).
// ---------------------------------------------------------------------------
#define LDP 1032   // P row stride in bf16 (1024 + 8 pad): 2-way-max banks
__launch_bounds__(256)
__global__ void attn_k(const unsigned short* __restrict__ Q,
                       const unsigned short* __restrict__ Kb,
                       const unsigned short* __restrict__ vt,
                       const float* __restrict__ xres,
                       float* __restrict__ attn_f,
                       float* __restrict__ out1) {
  const int b = blockIdx.y, h = blockIdx.z;
  const int q0 = blockIdx.x * 16;
  const int wave = threadIdx.x >> 6, lane = threadIdx.x & 63;
  const int quad = lane >> 4, l16 = lane & 15;
  __shared__ unsigned short PL[16 * LDP];
  __shared__ float red[4][16];

  // ---- scores: S[q0+.., :] = (Q*0.125) @ K^T  (Q pre-scaled) ----
  const unsigned short* Qb = Q + (long)b*SEQ*DM + h*DH;
  const unsigned short* Kh = Kb + (long)b*SEQ*DM + h*DH;
  s16x8 af[2];
#pragma unroll
  for (int ks = 0; ks < 2; ++ks)
    af[ks] = *(const s16x8*)&Qb[(long)(q0 + l16)*DM + ks*32 + quad*8];
  f32x4 acc[16];
#pragma unroll
  for (int nt = 0; nt < 16; ++nt) acc[nt] = (f32x4){0.f, 0.f, 0.f, 0.f};
  for (int nt = 0; nt < 16; ++nt) {
    const int kc = wave*256 + nt*16 + l16;
#pragma unroll
    for (int ks = 0; ks < 2; ++ks) {
      const s16x8 bfr = *(const s16x8*)&Kh[(long)kc*DM + ks*32 + quad*8];
      acc[nt] = __builtin_amdgcn_mfma_f32_16x16x32_bf16(af[ks], bfr, acc[nt], 0, 0, 0);
    }
  }

  // ---- softmax ----
  float rmax[4];
#pragma unroll
  for (int r = 0; r < 4; ++r) {
    float m = -3e38f;
#pragma unroll
    for (int nt = 0; nt < 16; ++nt) m = fmaxf(m, acc[nt][r]);
#pragma unroll
    for (int o = 1; o < 16; o <<= 1) m = fmaxf(m, __shfl_xor(m, o));
    rmax[r] = m;
  }
  if (l16 == 0) {
#pragma unroll
    for (int r = 0; r < 4; ++r) red[wave][quad*4 + r] = rmax[r];
  }
  __syncthreads();
#pragma unroll
  for (int r = 0; r < 4; ++r)
    rmax[r] = fmaxf(fmaxf(red[0][quad*4+r], red[1][quad*4+r]),
                    fmaxf(red[2][quad*4+r], red[3][quad*4+r]));
  __syncthreads();
#pragma unroll
  for (int r = 0; r < 4; ++r) {
    float s = 0.f;
#pragma unroll
    for (int nt = 0; nt < 16; ++nt) {
      const float e = __expf(acc[nt][r] - rmax[r]);
      acc[nt][r] = e; s += e;
    }
#pragma unroll
    for (int o = 1; o < 16; o <<= 1) s += __shfl_xor(s, o);
    if (l16 == 0) red[wave][quad*4 + r] = s;
  }
  __syncthreads();

  // ---- normalize, stage P (bf16) to LDS ----
#pragma unroll
  for (int r = 0; r < 4; ++r) {
    const float tot = red[0][quad*4+r] + red[1][quad*4+r] + red[2][quad*4+r] + red[3][quad*4+r];
    const float inv = 1.f / tot;
    unsigned short* prow = &PL[(quad*4 + r)*LDP + wave*256 + l16];
#pragma unroll
    for (int nt = 0; nt < 16; ++nt)
      prow[nt*16] = f2bf(acc[nt][r] * inv);
  }
  __syncthreads();

  // ---- attn output (f32), coalesced from LDS ----
  {
    const long obase = (long)(h*BSZ + b)*SEQ*SEQ + (long)q0*SEQ;
    const int col = threadIdx.x * 4;
#pragma unroll
    for (int row = 0; row < 16; ++row) {
      const ushort4 pv = *(const ushort4*)&PL[row*LDP + col];
      float4 o;
      o.x = bf2f(pv.x); o.y = bf2f(pv.y); o.z = bf2f(pv.z); o.w = bf2f(pv.w);
      ((float4*)(attn_f + obase + (long)row*SEQ))[threadIdx.x] = o;
    }
  }

  // ---- ctx = P @ V_h : wave owns output cols [wave*16, wave*16+16) ----
  f32x4 c = (f32x4){0.f, 0.f, 0.f, 0.f};
  const unsigned short* Vh = vt + (long)b*DM*SEQ + (long)(h*DH + wave*16 + l16)*SEQ;
#pragma unroll 4
  for (int k0 = 0; k0 < 32; ++k0) {
    const s16x8 a  = *(const s16x8*)&PL[l16*LDP + k0*32 + quad*8];
    const s16x8 bf = *(const s16x8*)&Vh[k0*32 + quad*8];
    c = __builtin_amdgcn_mfma_f32_16x16x32_bf16(a, bf, c, 0, 0, 0);
  }

  // ---- out1 = ctx + x ----
#pragma unroll
  for (int r = 0; r < 4; ++r) {
    const int gq = q0 + quad*4 + r;
    const int col = h*DH + wave*16 + l16;
    const long idx = (long)b*SEQ*DM + (long)gq*DM + col;
    out1[idx] = c[r] + xres[idx];
  }
}

extern "C" void kernel_launch(void* const* d_in, const int* in_sizes, int n_in,
                              void* d_out, int out_size, void* d_ws, size_t ws_size,
                              hipStream_t stream) {
  const float* x    = (const float*)d_in[0];
  const float* ln1g = (const float*)d_in[1];
  const float* ln1b = (const float*)d_in[2];
  const float* wq   = (const float*)d_in[3];
  const float* bq   = (const float*)d_in[4];
  const float* wk   = (const float*)d_in[5];
  const float* bk   = (const float*)d_in[6];
  const float* wv   = (const float*)d_in[7];
  const float* bv   = (const float*)d_in[8];
  const float* ln2g = (const float*)d_in[9];
  const float* ln2b = (const float*)d_in[10];
  const float* w1   = (const float*)d_in[11];
  const float* b1   = (const float*)d_in[12];
  const float* w2   = (const float*)d_in[13];
  const float* b2   = (const float*)d_in[14];
  float* out    = (float*)d_out;
  float* attn_f = out + (long)NTOK*DM;

  uint8_t* p = (uint8_t*)d_ws;
  auto alloc = [&](size_t bytes) {
    uint8_t* r = p; p += (bytes + 255) & ~(size_t)255; return r;
  };
  unsigned short* hbuf  = (unsigned short*)alloc((size_t)NTOK*DM*2);   // LN1(x)
  unsigned short* qkv   = (unsigned short*)alloc((size_t)3*NTOK*DM*2); // Q|K|V^T
  unsigned short* h2    = (unsigned short*)alloc((size_t)NTOK*DM*2);   // LN2(out1)
  unsigned short* f1    = (unsigned short*)alloc((size_t)NTOK*DF*2);   // relu(ff1)
  float*          out1  = (float*)alloc((size_t)NTOK*DM*4);            // ctx + x
  unsigned short* wqkvb = (unsigned short*)alloc((size_t)3*DM*DM*2);
  unsigned short* w1b   = (unsigned short*)alloc((size_t)DF*DM*2);
  unsigned short* w2b   = (unsigned short*)alloc((size_t)DM*DF*2);
  float*          bcat  = (float*)alloc((size_t)3*DM*4);

  // 1. all weights -> bf16 (QKV concatenated) + bias concat
  cvt5_k<<<CVT_BLOCKS, 256, 0, stream>>>(wq, wk, wv, w1, w2, bq, bk, bv,
                                         wqkvb, w1b, w2b, bcat);
  // 2. LN1
  ln_k<<<NTOK, 256, 0, stream>>>(x, ln1g, ln1b, hbuf);

  // 3. fused QKV projection (Q pre-scaled 1/8, V stored transposed)
  gemm_k<128,128,64,64,5><<<dim3((NTOK/128)*(3*DM/128)), 256, 0, stream>>>(
      hbuf, wqkvb, bcat, qkv, nullptr, 3*DM/128, DM, DM, DM, DM, 0.125f);

  // 4. fused scores + softmax + attn write + PV + residual
  attn_k<<<dim3(SEQ/16, BSZ, NH), 256, 0, stream>>>(
      qkv, qkv + QKVSZ, qkv + 2*QKVSZ, x, attn_f, out1);

  // 5. LN2
  ln_k<<<NTOK, 256, 0, stream>>>(out1, ln2g, ln2b, h2);

  // 6. ff1 = relu(h2 @ w1^T + b1)
  gemm_k<128,128,64,64,1><<<dim3((NTOK/128)*(DF/128)), 256, 0, stream>>>(
      h2, w1b, b1, f1, nullptr, DF/128, DM, DM, DM, DF, 1.f);

  // 7. out = ff1 @ w2^T + b2 + out1 -> d_out
  gemm_k<128,128,64,64,3><<<dim3((NTOK/128)*(DM/128)), 256, 0, stream>>>(
      f1, w2b, b2, out, out1, DM/128, DF, DF, DF, DM, 1.f);
}